// Round 3
// baseline (322.477 us; speedup 1.0000x reference)
//
#include <hip/hip_runtime.h>
#include <hip/hip_bf16.h>

// Problem constants
#define N_TOK   16384      // B*T
#define HDIM    2048       // H*d_h
#define NH      16
#define DH      128
#define NPAIRS  120
#define KCHUNKS 8
#define NKT     (N_TOK / 64)            // 256 k-tiles of 64 tokens
#define KT_PER_CHUNK (NKT / KCHUNKS)    // 32 (64-token panels per chunk)
#define KT128_PER_CHUNK (KT_PER_CHUNK / 2)  // 16 (128-token MX steps per chunk)
#define PANEL_BYTES 8192                // 128 c-rows x 64 tokens x 1B (fp8)

// Workspace layout (bytes) — total ~41.5 MB
#define SUM_OFF    0u
#define SUMSQ_OFF  8192u
#define PC_OFF     36864u                     // 120*128*128 f32 = 7,864,320 B
#define XT_OFF     7901184u                   // 2048*16384 fp8 = 33,554,432 B

typedef float f32x4 __attribute__((ext_vector_type(4)));
typedef int   v8i   __attribute__((ext_vector_type(8)));
typedef long long i64t;

// ---------------------------------------------------------------- fp8 e4m3 pack
#if __has_builtin(__builtin_amdgcn_cvt_pk_fp8_f32)
__device__ __forceinline__ unsigned pk4_fp8(float a, float b, float c, float d) {
    int w = __builtin_amdgcn_cvt_pk_fp8_f32(a, b, 0, false);   // bytes 0,1
    w = __builtin_amdgcn_cvt_pk_fp8_f32(c, d, w, true);        // bytes 2,3
    return (unsigned)w;
}
#else
__device__ __forceinline__ unsigned char f2e4m3_sw(float f) {
    unsigned u = __float_as_uint(f);
    unsigned s = (u >> 24) & 0x80u;
    unsigned a = u & 0x7fffffffu;
    if (a >= 0x43e00000u) return (unsigned char)(s | 0x7eu);   // clamp to 448
    if (a < 0x3c800000u) {                                     // |x| < 2^-6: subnormal
        float av = __uint_as_float(a);
        int q = (int)rintf(av * 512.0f);                       // units of 2^-9
        return (unsigned char)(s | (unsigned)q);               // q==8 -> 0x08 == 2^-6 normal
    }
    unsigned lsb = (a >> 20) & 1u;
    a += 0x7ffffu + lsb;                                       // RNE to 3 mantissa bits
    int e8 = (int)(a >> 23) - 120;                             // -127 + 7
    unsigned m = (a >> 20) & 7u;
    return (unsigned char)(s | ((unsigned)e8 << 3) | m);
}
__device__ __forceinline__ unsigned pk4_fp8(float a, float b, float c, float d) {
    return (unsigned)f2e4m3_sw(a) | ((unsigned)f2e4m3_sw(b) << 8) |
           ((unsigned)f2e4m3_sw(c) << 16) | ((unsigned)f2e4m3_sw(d) << 24);
}
#endif

// ---------------------------------------------------------------- pass 1: fused stats + panelized transpose + fp8
// Block = one 8 KB panel: head h, tokens n0..n0+63, all 128 head-dims.
// Rows with (c>>3)&1 store their two 8B halves SWAPPED, so the gram kernel's
// LDS read swizzle can include r-bit-3 -> conflict-free ds_read_b64.
__global__ __launch_bounds__(256)
void stats_transpose_kernel(const float* __restrict__ X,
                            float* __restrict__ sum, float* __restrict__ sumsq,
                            unsigned char* __restrict__ Xt) {
    __shared__ float tile[64][129];               // stride 129
    __shared__ float sred[4][32][8];              // cross-wave stats partials
    const int h  = blockIdx.x;                    // 0..15
    const int by = blockIdx.y;                    // 0..255
    const int n0 = by * 64;
    const int tx = threadIdx.x;
    const int w  = tx >> 6, l = tx & 63;
    const int cq = tx & 31;                       // float4 index within 128-col slice
    const int rq0 = tx >> 5;                      // 0..7

    float4 s  = make_float4(0.f, 0.f, 0.f, 0.f);
    float4 ss = make_float4(0.f, 0.f, 0.f, 0.f);
    #pragma unroll
    for (int it = 0; it < 8; ++it) {
        int r = it * 8 + rq0;
        float4 x = *(const float4*)(X + (size_t)(n0 + r) * HDIM + h * DH + cq * 4);
        s.x += x.x; s.y += x.y; s.z += x.z; s.w += x.w;
        ss.x += x.x * x.x; ss.y += x.y * x.y; ss.z += x.z * x.z; ss.w += x.w * x.w;
        tile[r][cq * 4 + 0] = x.x; tile[r][cq * 4 + 1] = x.y;
        tile[r][cq * 4 + 2] = x.z; tile[r][cq * 4 + 3] = x.w;
    }
    s.x += __shfl_down(s.x, 32);  s.y += __shfl_down(s.y, 32);
    s.z += __shfl_down(s.z, 32);  s.w += __shfl_down(s.w, 32);
    ss.x += __shfl_down(ss.x, 32); ss.y += __shfl_down(ss.y, 32);
    ss.z += __shfl_down(ss.z, 32); ss.w += __shfl_down(ss.w, 32);
    if (l < 32) {
        sred[w][l][0] = s.x;  sred[w][l][1] = s.y;
        sred[w][l][2] = s.z;  sred[w][l][3] = s.w;
        sred[w][l][4] = ss.x; sred[w][l][5] = ss.y;
        sred[w][l][6] = ss.z; sred[w][l][7] = ss.w;
    }
    __syncthreads();
    if (tx < 32) {                                // wave 0 finishes stats
        float a0 = 0.f, a1 = 0.f, a2 = 0.f, a3 = 0.f;
        float b0 = 0.f, b1 = 0.f, b2 = 0.f, b3 = 0.f;
        #pragma unroll
        for (int w2 = 0; w2 < 4; ++w2) {
            a0 += sred[w2][tx][0]; a1 += sred[w2][tx][1];
            a2 += sred[w2][tx][2]; a3 += sred[w2][tx][3];
            b0 += sred[w2][tx][4]; b1 += sred[w2][tx][5];
            b2 += sred[w2][tx][6]; b3 += sred[w2][tx][7];
        }
        int c = h * DH + tx * 4;
        atomicAdd(&sum[c + 0], a0);  atomicAdd(&sum[c + 1], a1);
        atomicAdd(&sum[c + 2], a2);  atomicAdd(&sum[c + 3], a3);
        atomicAdd(&sumsq[c + 0], b0); atomicAdd(&sumsq[c + 1], b1);
        atomicAdd(&sumsq[c + 2], b2); atomicAdd(&sumsq[c + 3], b3);
    }
    // transpose write: 512 16B-chunks (one panel), contiguous per wave-instruction
    unsigned char* panel = Xt + ((size_t)h * NKT + by) * PANEL_BYTES;
    #pragma unroll
    for (int it = 0; it < 2; ++it) {
        int q = it * 256 + tx;
        int c = q >> 2, o = q & 3;                // chunk = (dim c, tokens 16o..16o+15)
        uint4 pk;
        pk.x = pk4_fp8(tile[o*16+ 0][c], tile[o*16+ 1][c], tile[o*16+ 2][c], tile[o*16+ 3][c]);
        pk.y = pk4_fp8(tile[o*16+ 4][c], tile[o*16+ 5][c], tile[o*16+ 6][c], tile[o*16+ 7][c]);
        pk.z = pk4_fp8(tile[o*16+ 8][c], tile[o*16+ 9][c], tile[o*16+10][c], tile[o*16+11][c]);
        pk.w = pk4_fp8(tile[o*16+12][c], tile[o*16+13][c], tile[o*16+14][c], tile[o*16+15][c]);
        // r-bit-3 half-swap: bakes the missing swizzle bit into the data so the
        // consumer's bank index depends on all 4 low row bits.
        uint4 outv = ((c >> 3) & 1) ? make_uint4(pk.z, pk.w, pk.x, pk.y) : pk;
        *(uint4*)(panel + c * 64 + o * 16) = outv;
    }
}

// ---------------------------------------------------------------- pass 3: pairwise raw Gram via MX-fp8 MFMA (K=128)
// m148-proven shape: 128x128 tile, single-buffered 32 KB LDS (A0,A1,B0,B1 panels),
// 2-barrier loop, 16 x mfma_scale_f32_16x16x128_f8f6f4 per 128-token step with
// unity e8m0 scales (0x7F). LDS layout: physical 8B unit p of row r holds logical
// unit p ^ (r&6) ^ ((r>>3)&1) (chunk swizzle via global src addr + pass-1 half-swap);
// reader XORs the same involution -> conflict-free and k-consistent across rows.
__device__ __forceinline__ void gload16(const void* gsrc, void* ldst) {
    __builtin_amdgcn_global_load_lds(
        (const __attribute__((address_space(1))) unsigned int*)gsrc,
        (__attribute__((address_space(3))) unsigned int*)ldst,
        16, 0, 0);
}

__global__ __launch_bounds__(256, 4)
void gram_kernel(const unsigned char* __restrict__ Xt, float* __restrict__ pairC) {
    const int kc = blockIdx.x;                    // K-chunk 0..7 -> XCD kc (linear%8)
    const int p  = blockIdx.y;                    // pair 0..119
    int i = 0, rem = p;
    while (rem >= NH - 1 - i) { rem -= NH - 1 - i; ++i; }
    const int j = i + 1 + rem;

    // single buffer: [A0|A1|B0|B1] 8 KB panels = 32 KB -> 4 blocks/CU
    __shared__ alignas(16) unsigned char lds[4 * PANEL_BYTES];

    const int tx = threadIdx.x;
    const int w  = tx >> 6, l = tx & 63;
    const int wm = w >> 1, wn = w & 1;            // 2x2 wave grid over 128x128
    const int l15 = l & 15, quad = l >> 4;

    // Staging source swizzle (16B chunk level): cc = cl ^ ((r>>1)&3)
    unsigned int goff0, goff1;
    {
        int r0 = tx >> 2, cl0 = tx & 3;
        goff0 = (unsigned int)(r0 * 64 + (cl0 ^ ((r0 >> 1) & 3)) * 16);
        int cfl = 256 + tx;
        int r1 = cfl >> 2, cl1 = cfl & 3;
        goff1 = (unsigned int)(r1 * 64 + (cl1 ^ ((r1 >> 1) & 3)) * 16);
    }
    const int lo0 = w * 1024;                     // wave-uniform LDS base, issue 0
    const int lo1 = 4096 + w * 1024;              // issue 1
    const char* Abase = (const char*)Xt + ((size_t)i * NKT + (size_t)kc * KT_PER_CHUNK) * PANEL_BYTES;
    const char* Bbase = (const char*)Xt + ((size_t)j * NKT + (size_t)kc * KT_PER_CHUNK) * PANEL_BYTES;

    f32x4 acc[4][4];
    #pragma unroll
    for (int mi = 0; mi < 4; ++mi)
        #pragma unroll
        for (int ni = 0; ni < 4; ++ni)
            acc[mi][ni] = (f32x4){0.f, 0.f, 0.f, 0.f};

    // Row-dependent unit swizzle (r == l15 mod 16 within a fragment)
    const int usw = (l15 & 6) | (l15 >> 3);
    const int selP = quad >> 1;                   // 64-token panel within the 128-step
    const int ub   = (quad & 1) * 4;              // logical 8B-unit base within panel
    // physical byte offsets of the 4 logical units (lane constants)
    const int puo0 = ((ub + 0) ^ usw) * 8;
    const int puo1 = ((ub + 1) ^ usw) * 8;
    const int puo2 = ((ub + 2) ^ usw) * 8;
    const int puo3 = ((ub + 3) ^ usw) * 8;
    const unsigned char* laP = lds + selP * PANEL_BYTES;                   // A panel base
    const unsigned char* lbP = lds + 2 * PANEL_BYTES + selP * PANEL_BYTES; // B panel base
    const int rowA = (wm * 64 + l15) * 64;        // + mi*1024
    const int rowB = (wn * 64 + l15) * 64;        // + ni*1024

    for (int kt = 0; kt < KT128_PER_CHUNK; ++kt) {
        // ---- stage 4 panels (A0,A1,B0,B1) = 32 KB, 8 x gload16/thread
        {
            const char* pa = Abase + (size_t)(kt * 2) * PANEL_BYTES;
            const char* pb = Bbase + (size_t)(kt * 2) * PANEL_BYTES;
            gload16(pa + goff0,               (char*)lds + lo0);
            gload16(pa + goff1,               (char*)lds + lo1);
            gload16(pa + PANEL_BYTES + goff0, (char*)lds + PANEL_BYTES + lo0);
            gload16(pa + PANEL_BYTES + goff1, (char*)lds + PANEL_BYTES + lo1);
            gload16(pb + goff0,               (char*)lds + 2 * PANEL_BYTES + lo0);
            gload16(pb + goff1,               (char*)lds + 2 * PANEL_BYTES + lo1);
            gload16(pb + PANEL_BYTES + goff0, (char*)lds + 3 * PANEL_BYTES + lo0);
            gload16(pb + PANEL_BYTES + goff1, (char*)lds + 3 * PANEL_BYTES + lo1);
        }
        asm volatile("s_waitcnt vmcnt(0)\n\ts_barrier" ::: "memory");

        // ---- load A fragments (k-ordered gather of 4 swizzled 8B units each)
        v8i a[4];
        #pragma unroll
        for (int mi = 0; mi < 4; ++mi) {
            const unsigned char* rp = laP + rowA + mi * 1024;
            union { v8i v; i64t d[4]; } u;
            u.d[0] = *(const i64t*)(rp + puo0);
            u.d[1] = *(const i64t*)(rp + puo1);
            u.d[2] = *(const i64t*)(rp + puo2);
            u.d[3] = *(const i64t*)(rp + puo3);
            a[mi] = u.v;
        }
        // ---- B fragment per column, 4 MFMAs each (keeps VGPR pressure low)
        #pragma unroll
        for (int ni = 0; ni < 4; ++ni) {
            const unsigned char* rp = lbP + rowB + ni * 1024;
            union { v8i v; i64t d[4]; } u;
            u.d[0] = *(const i64t*)(rp + puo0);
            u.d[1] = *(const i64t*)(rp + puo1);
            u.d[2] = *(const i64t*)(rp + puo2);
            u.d[3] = *(const i64t*)(rp + puo3);
            v8i b = u.v;
            #pragma unroll
            for (int mi = 0; mi < 4; ++mi)
                acc[mi][ni] = __builtin_amdgcn_mfma_scale_f32_16x16x128_f8f6f4(
                    a[mi], b, acc[mi][ni], 0, 0,
                    0, 0x7F7F7F7F, 0, 0x7F7F7F7F);   // unity e8m0 scales
        }

        // ---- all LDS reads retired before next stage overwrites
        if (kt + 1 < KT128_PER_CHUNK) {
            asm volatile("s_waitcnt lgkmcnt(0)\n\ts_barrier" ::: "memory");
        }
    }

    // Epilogue: partial raw Gram -> atomic accumulate (KCHUNKS contenders/address)
    float* pc = pairC + (size_t)p * (DH * DH);
    #pragma unroll
    for (int mi = 0; mi < 4; ++mi)
        #pragma unroll
        for (int ni = 0; ni < 4; ++ni)
            #pragma unroll
            for (int r = 0; r < 4; ++r) {
                int row = wm * 64 + mi * 16 + quad * 4 + r;  // d (head-i dim)
                int col = wn * 64 + ni * 16 + l15;           // e (head-j dim)
                atomicAdd(&pc[row * DH + col], acc[mi][ni][r]);
            }
}

// ---------------------------------------------------------------- pass 4: per-pair loss + final accumulate
// (finalize fused: mu/rinv computed inline from sum/sumsq)
__global__ void pair_reduce_kernel(const float* __restrict__ pairC, const float* __restrict__ G,
                                   const float* __restrict__ sum, const float* __restrict__ sumsq,
                                   float* __restrict__ out) {
    int p = blockIdx.x;
    int i = 0, rem = p;
    while (rem >= NH - 1 - i) { rem -= NH - 1 - i; ++i; }
    int j = i + 1 + rem;
    __shared__ float smui[DH], smuj[DH], sri[DH], srj[DH];
    {
        int t = threadIdx.x;
        int head = (t < DH) ? i : j;
        int d = t & (DH - 1);
        int c = head * DH + d;
        float m = sum[c] * (1.f / (float)N_TOK);
        float var = (sumsq[c] - (float)N_TOK * m * m) * (1.f / (float)(N_TOK - 1));
        var = fmaxf(var, 0.f);
        float r = 1.f / (sqrtf(var) + 1e-8f);
        if (t < DH) { smui[d] = m; sri[d] = r; }
        else        { smuj[d] = m; srj[d] = r; }
    }
    __syncthreads();
    const float invN = 1.f / (float)N_TOK;
    const float* pc = pairC + (size_t)p * (DH * DH);
    float s = 0.f;
    for (int idx = threadIdx.x; idx < DH * DH; idx += 256) {
        int d = idx >> 7, e = idx & 127;
        float cn = (pc[idx] * invN - smui[d] * smuj[e]) * sri[d] * srj[e];
        float diff = cn - ((d == e) ? 1.f : 0.f);
        s += diff * diff;
    }
    for (int o = 32; o; o >>= 1) s += __shfl_down(s, o);
    __shared__ float red[4];
    if ((threadIdx.x & 63) == 0) red[threadIdx.x >> 6] = s;
    __syncthreads();
    if (threadIdx.x == 0) {
        float t = red[0] + red[1] + red[2] + red[3];
        float x = -15.99f * (G[i * NH + j] - 0.0f);
        float sp = (x > 20.f) ? x : log1pf(expf(x));
        float wgt = 0.929f + (1.f - 0.929f) * sp;
        atomicAdd(out, wgt * t * (1.f / (float)NPAIRS));
    }
}

// ---------------------------------------------------------------- launcher
extern "C" void kernel_launch(void* const* d_in, const int* in_sizes, int n_in,
                              void* d_out, int out_size, void* d_ws, size_t ws_size,
                              hipStream_t stream) {
    const float* X = (const float*)d_in[0];
    const float* G = (const float*)d_in[1];
    float* out = (float*)d_out;
    char* ws = (char*)d_ws;

    float*         sum   = (float*)(ws + SUM_OFF);
    float*         sumsq = (float*)(ws + SUMSQ_OFF);
    float*         pairC = (float*)(ws + PC_OFF);
    unsigned char* Xt    = (unsigned char*)(ws + XT_OFF);

    hipMemsetAsync(ws + SUM_OFF, 0, 16384, stream);                     // sum+sumsq
    hipMemsetAsync(ws + PC_OFF, 0, (size_t)NPAIRS * DH * DH * 4, stream);
    hipMemsetAsync(d_out, 0, 4, stream);

    stats_transpose_kernel<<<dim3(16, 256), 256, 0, stream>>>(X, sum, sumsq, Xt);
    gram_kernel<<<dim3(KCHUNKS, NPAIRS), 256, 0, stream>>>(Xt, pairC);
    pair_reduce_kernel<<<NPAIRS, 256, 0, stream>>>(pairC, G, sum, sumsq, out);
}

// Round 4
// 288.293 us; speedup vs baseline: 1.1186x; 1.1186x over previous
//
#include <hip/hip_runtime.h>
#include <hip/hip_bf16.h>

// Problem constants
#define N_TOK   16384      // B*T
#define HDIM    2048       // H*d_h
#define NH      16
#define DH      128
#define NPAIRS  120
#define KCHUNKS 8
#define NKT     (N_TOK / 64)            // 256 k-tiles of 64 tokens
#define KT_PER_CHUNK (NKT / KCHUNKS)    // 32 (64-token panels per chunk)
#define KT128_PER_CHUNK (KT_PER_CHUNK / 2)  // 16 (128-token MX steps per chunk)
#define PANEL_BYTES 8192                // 128 c-rows x 64 tokens x 1B (fp8)

// Workspace layout (bytes) — total ~41.5 MB
#define SUM_OFF    0u
#define SUMSQ_OFF  8192u
#define PC_OFF     36864u                     // 120*128*128 f32 = 7,864,320 B
#define XT_OFF     7901184u                   // 2048*16384 fp8 = 33,554,432 B

typedef float f32x4 __attribute__((ext_vector_type(4)));
typedef int   v8i   __attribute__((ext_vector_type(8)));
typedef int   v2i   __attribute__((ext_vector_type(2)));
typedef long long i64t;

// ---------------------------------------------------------------- fp8 e4m3 pack
#if __has_builtin(__builtin_amdgcn_cvt_pk_fp8_f32)
__device__ __forceinline__ unsigned pk4_fp8(float a, float b, float c, float d) {
    int w = __builtin_amdgcn_cvt_pk_fp8_f32(a, b, 0, false);   // bytes 0,1
    w = __builtin_amdgcn_cvt_pk_fp8_f32(c, d, w, true);        // bytes 2,3
    return (unsigned)w;
}
#else
__device__ __forceinline__ unsigned char f2e4m3_sw(float f) {
    unsigned u = __float_as_uint(f);
    unsigned s = (u >> 24) & 0x80u;
    unsigned a = u & 0x7fffffffu;
    if (a >= 0x43e00000u) return (unsigned char)(s | 0x7eu);   // clamp to 448
    if (a < 0x3c800000u) {                                     // |x| < 2^-6: subnormal
        float av = __uint_as_float(a);
        int q = (int)rintf(av * 512.0f);                       // units of 2^-9
        return (unsigned char)(s | (unsigned)q);               // q==8 -> 0x08 == 2^-6 normal
    }
    unsigned lsb = (a >> 20) & 1u;
    a += 0x7ffffu + lsb;                                       // RNE to 3 mantissa bits
    int e8 = (int)(a >> 23) - 120;                             // -127 + 7
    unsigned m = (a >> 20) & 7u;
    return (unsigned char)(s | ((unsigned)e8 << 3) | m);
}
__device__ __forceinline__ unsigned pk4_fp8(float a, float b, float c, float d) {
    return (unsigned)f2e4m3_sw(a) | ((unsigned)f2e4m3_sw(b) << 8) |
           ((unsigned)f2e4m3_sw(c) << 16) | ((unsigned)f2e4m3_sw(d) << 24);
}
#endif

// ---------------------------------------------------------------- pass 1: fused stats + panelized transpose + fp8
// Block = one 8 KB panel: head h, tokens n0..n0+63, all 128 head-dims.
// Rows with (c>>3)&1 store their two 8B halves SWAPPED, so the gram kernel's
// LDS read swizzle can include r-bit-3 -> conflict-free ds_read_b64.
__global__ __launch_bounds__(256)
void stats_transpose_kernel(const float* __restrict__ X,
                            float* __restrict__ sum, float* __restrict__ sumsq,
                            unsigned char* __restrict__ Xt) {
    __shared__ float tile[64][129];               // stride 129
    __shared__ float sred[4][32][8];              // cross-wave stats partials
    const int h  = blockIdx.x;                    // 0..15
    const int by = blockIdx.y;                    // 0..255
    const int n0 = by * 64;
    const int tx = threadIdx.x;
    const int w  = tx >> 6, l = tx & 63;
    const int cq = tx & 31;                       // float4 index within 128-col slice
    const int rq0 = tx >> 5;                      // 0..7

    float4 s  = make_float4(0.f, 0.f, 0.f, 0.f);
    float4 ss = make_float4(0.f, 0.f, 0.f, 0.f);
    #pragma unroll
    for (int it = 0; it < 8; ++it) {
        int r = it * 8 + rq0;
        float4 x = *(const float4*)(X + (size_t)(n0 + r) * HDIM + h * DH + cq * 4);
        s.x += x.x; s.y += x.y; s.z += x.z; s.w += x.w;
        ss.x += x.x * x.x; ss.y += x.y * x.y; ss.z += x.z * x.z; ss.w += x.w * x.w;
        tile[r][cq * 4 + 0] = x.x; tile[r][cq * 4 + 1] = x.y;
        tile[r][cq * 4 + 2] = x.z; tile[r][cq * 4 + 3] = x.w;
    }
    s.x += __shfl_down(s.x, 32);  s.y += __shfl_down(s.y, 32);
    s.z += __shfl_down(s.z, 32);  s.w += __shfl_down(s.w, 32);
    ss.x += __shfl_down(ss.x, 32); ss.y += __shfl_down(ss.y, 32);
    ss.z += __shfl_down(ss.z, 32); ss.w += __shfl_down(ss.w, 32);
    if (l < 32) {
        sred[w][l][0] = s.x;  sred[w][l][1] = s.y;
        sred[w][l][2] = s.z;  sred[w][l][3] = s.w;
        sred[w][l][4] = ss.x; sred[w][l][5] = ss.y;
        sred[w][l][6] = ss.z; sred[w][l][7] = ss.w;
    }
    __syncthreads();
    if (tx < 32) {                                // wave 0 finishes stats
        float a0 = 0.f, a1 = 0.f, a2 = 0.f, a3 = 0.f;
        float b0 = 0.f, b1 = 0.f, b2 = 0.f, b3 = 0.f;
        #pragma unroll
        for (int w2 = 0; w2 < 4; ++w2) {
            a0 += sred[w2][tx][0]; a1 += sred[w2][tx][1];
            a2 += sred[w2][tx][2]; a3 += sred[w2][tx][3];
            b0 += sred[w2][tx][4]; b1 += sred[w2][tx][5];
            b2 += sred[w2][tx][6]; b3 += sred[w2][tx][7];
        }
        int c = h * DH + tx * 4;
        atomicAdd(&sum[c + 0], a0);  atomicAdd(&sum[c + 1], a1);
        atomicAdd(&sum[c + 2], a2);  atomicAdd(&sum[c + 3], a3);
        atomicAdd(&sumsq[c + 0], b0); atomicAdd(&sumsq[c + 1], b1);
        atomicAdd(&sumsq[c + 2], b2); atomicAdd(&sumsq[c + 3], b3);
    }
    // transpose write: 512 16B-chunks (one panel), contiguous per wave-instruction
    unsigned char* panel = Xt + ((size_t)h * NKT + by) * PANEL_BYTES;
    #pragma unroll
    for (int it = 0; it < 2; ++it) {
        int q = it * 256 + tx;
        int c = q >> 2, o = q & 3;                // chunk = (dim c, tokens 16o..16o+15)
        uint4 pk;
        pk.x = pk4_fp8(tile[o*16+ 0][c], tile[o*16+ 1][c], tile[o*16+ 2][c], tile[o*16+ 3][c]);
        pk.y = pk4_fp8(tile[o*16+ 4][c], tile[o*16+ 5][c], tile[o*16+ 6][c], tile[o*16+ 7][c]);
        pk.z = pk4_fp8(tile[o*16+ 8][c], tile[o*16+ 9][c], tile[o*16+10][c], tile[o*16+11][c]);
        pk.w = pk4_fp8(tile[o*16+12][c], tile[o*16+13][c], tile[o*16+14][c], tile[o*16+15][c]);
        // r-bit-3 half-swap: bakes the missing swizzle bit into the data so the
        // consumer's bank index depends on all 4 low row bits.
        uint4 outv = ((c >> 3) & 1) ? make_uint4(pk.z, pk.w, pk.x, pk.y) : pk;
        *(uint4*)(panel + c * 64 + o * 16) = outv;
    }
}

// ---------------------------------------------------------------- pass 3: pairwise raw Gram via MX-fp8 MFMA (K=128)
// 128x128 tile, DOUBLE-buffered 2x32 KB LDS, 2-phase prefetch pipeline,
// 16 x mfma_scale_f32_16x16x128_f8f6f4 per 128-token step, unity e8m0 scales.
// LDS layout: physical 8B unit p of row r holds logical unit p ^ (r&6) ^ ((r>>3)&1).
// launch_bounds(256,2): 256-reg unified cap — (256,4)'s 128-reg cap forced the
// K=128 fragments to scratch in round 3 (WRITE_SIZE 61->207 MB). // <- lesson
__device__ __forceinline__ void gload16(const void* gsrc, void* ldst) {
    __builtin_amdgcn_global_load_lds(
        (const __attribute__((address_space(1))) unsigned int*)gsrc,
        (__attribute__((address_space(3))) unsigned int*)ldst,
        16, 0, 0);
}

// Register-resident gather: 4x ds_read_b64 -> v8i via constant-index inserts
// (NO union aggregate — that allocated in scratch).
__device__ __forceinline__ v8i gather_frag(const unsigned char* rp,
                                           int o0, int o1, int o2, int o3) {
    v2i x0 = *(const v2i*)(rp + o0);
    v2i x1 = *(const v2i*)(rp + o1);
    v2i x2 = *(const v2i*)(rp + o2);
    v2i x3 = *(const v2i*)(rp + o3);
    v8i r;
    r[0] = x0[0]; r[1] = x0[1];
    r[2] = x1[0]; r[3] = x1[1];
    r[4] = x2[0]; r[5] = x2[1];
    r[6] = x3[0]; r[7] = x3[1];
    return r;
}

__global__ __launch_bounds__(256, 2)
void gram_kernel(const unsigned char* __restrict__ Xt, float* __restrict__ pairC) {
    const int kc = blockIdx.x;                    // K-chunk 0..7 -> XCD kc (linear%8)
    const int p  = blockIdx.y;                    // pair 0..119
    int i = 0, rem = p;
    while (rem >= NH - 1 - i) { rem -= NH - 1 - i; ++i; }
    const int j = i + 1 + rem;

    // double buffer: 2 x [A0|A1|B0|B1] = 64 KB -> 2 blocks/CU
    __shared__ alignas(16) unsigned char lds[2 * 4 * PANEL_BYTES];

    const int tx = threadIdx.x;
    const int w  = tx >> 6, l = tx & 63;
    const int wm = w >> 1, wn = w & 1;            // 2x2 wave grid over 128x128
    const int l15 = l & 15, quad = l >> 4;

    // Staging source swizzle (16B chunk level): cc = cl ^ ((r>>1)&3)
    unsigned int goff0, goff1;
    {
        int r0 = tx >> 2, cl0 = tx & 3;
        goff0 = (unsigned int)(r0 * 64 + (cl0 ^ ((r0 >> 1) & 3)) * 16);
        int cfl = 256 + tx;
        int r1 = cfl >> 2, cl1 = cfl & 3;
        goff1 = (unsigned int)(r1 * 64 + (cl1 ^ ((r1 >> 1) & 3)) * 16);
    }
    const int lo0 = w * 1024;                     // wave-uniform LDS base, issue 0
    const int lo1 = 4096 + w * 1024;              // issue 1
    const char* Abase = (const char*)Xt + ((size_t)i * NKT + (size_t)kc * KT_PER_CHUNK) * PANEL_BYTES;
    const char* Bbase = (const char*)Xt + ((size_t)j * NKT + (size_t)kc * KT_PER_CHUNK) * PANEL_BYTES;

    // stage one 128-token step (4 panels, 32 KB) into buffer at `base`
    auto STAGE = [&](int kt2, char* base) {
        const char* pa = Abase + (size_t)(kt2 * 2) * PANEL_BYTES;
        const char* pb = Bbase + (size_t)(kt2 * 2) * PANEL_BYTES;
        gload16(pa + goff0,               base + lo0);
        gload16(pa + goff1,               base + lo1);
        gload16(pa + PANEL_BYTES + goff0, base + PANEL_BYTES + lo0);
        gload16(pa + PANEL_BYTES + goff1, base + PANEL_BYTES + lo1);
        gload16(pb + goff0,               base + 2 * PANEL_BYTES + lo0);
        gload16(pb + goff1,               base + 2 * PANEL_BYTES + lo1);
        gload16(pb + PANEL_BYTES + goff0, base + 3 * PANEL_BYTES + lo0);
        gload16(pb + PANEL_BYTES + goff1, base + 3 * PANEL_BYTES + lo1);
    };

    f32x4 acc[4][4];
    #pragma unroll
    for (int mi = 0; mi < 4; ++mi)
        #pragma unroll
        for (int ni = 0; ni < 4; ++ni)
            acc[mi][ni] = (f32x4){0.f, 0.f, 0.f, 0.f};

    // Row-dependent unit swizzle (r == l15 mod 16 within a fragment)
    const int usw = (l15 & 6) | (l15 >> 3);
    const int selP = quad >> 1;                   // 64-token panel within the 128-step
    const int ub   = (quad & 1) * 4;              // logical 8B-unit base within panel
    // physical byte offsets of the 4 logical units (lane constants)
    const int puo0 = ((ub + 0) ^ usw) * 8;
    const int puo1 = ((ub + 1) ^ usw) * 8;
    const int puo2 = ((ub + 2) ^ usw) * 8;
    const int puo3 = ((ub + 3) ^ usw) * 8;
    const int rowA = (wm * 64 + l15) * 64;        // + mi*1024
    const int rowB = (wn * 64 + l15) * 64;        // + ni*1024
    const int offA = selP * PANEL_BYTES + rowA;
    const int offB = 2 * PANEL_BYTES + selP * PANEL_BYTES + rowB;

    // ---- prologue: stage step 0 into buf 0, drain, barrier
    STAGE(0, (char*)lds);
    asm volatile("s_waitcnt vmcnt(0)\n\ts_barrier" ::: "memory");

    int cur = 0;
    for (int kt = 0; kt < KT128_PER_CHUNK; ++kt) {
        // ---- prefetch next step into the other buffer
        if (kt + 1 < KT128_PER_CHUNK)
            STAGE(kt + 1, (char*)lds + (cur ^ 1) * (4 * PANEL_BYTES));

        // ---- compute current buffer
        const unsigned char* bufb = lds + cur * (4 * PANEL_BYTES);
        const unsigned char* laP = bufb + offA;
        const unsigned char* lbP = bufb + offB;

        v8i a0 = gather_frag(laP + 0 * 1024, puo0, puo1, puo2, puo3);
        v8i a1 = gather_frag(laP + 1 * 1024, puo0, puo1, puo2, puo3);
        v8i a2 = gather_frag(laP + 2 * 1024, puo0, puo1, puo2, puo3);
        v8i a3 = gather_frag(laP + 3 * 1024, puo0, puo1, puo2, puo3);
        #pragma unroll
        for (int ni = 0; ni < 4; ++ni) {
            v8i b = gather_frag(lbP + ni * 1024, puo0, puo1, puo2, puo3);
            acc[0][ni] = __builtin_amdgcn_mfma_scale_f32_16x16x128_f8f6f4(
                a0, b, acc[0][ni], 0, 0, 0, 0x7F7F7F7F, 0, 0x7F7F7F7F);
            acc[1][ni] = __builtin_amdgcn_mfma_scale_f32_16x16x128_f8f6f4(
                a1, b, acc[1][ni], 0, 0, 0, 0x7F7F7F7F, 0, 0x7F7F7F7F);
            acc[2][ni] = __builtin_amdgcn_mfma_scale_f32_16x16x128_f8f6f4(
                a2, b, acc[2][ni], 0, 0, 0, 0x7F7F7F7F, 0, 0x7F7F7F7F);
            acc[3][ni] = __builtin_amdgcn_mfma_scale_f32_16x16x128_f8f6f4(
                a3, b, acc[3][ni], 0, 0, 0, 0x7F7F7F7F, 0, 0x7F7F7F7F);
        }

        // ---- end-of-iter: prefetched loads landed (latency hidden by MFMA),
        //      our ds_reads retired, one barrier. No drain before compute.
        if (kt + 1 < KT128_PER_CHUNK)
            asm volatile("s_waitcnt vmcnt(0) lgkmcnt(0)\n\ts_barrier" ::: "memory");
        cur ^= 1;
    }

    // Epilogue: partial raw Gram -> atomic accumulate (KCHUNKS contenders/address)
    float* pc = pairC + (size_t)p * (DH * DH);
    #pragma unroll
    for (int mi = 0; mi < 4; ++mi)
        #pragma unroll
        for (int ni = 0; ni < 4; ++ni)
            #pragma unroll
            for (int r = 0; r < 4; ++r) {
                int row = wm * 64 + mi * 16 + quad * 4 + r;  // d (head-i dim)
                int col = wn * 64 + ni * 16 + l15;           // e (head-j dim)
                atomicAdd(&pc[row * DH + col], acc[mi][ni][r]);
            }
}

// ---------------------------------------------------------------- pass 4: per-pair loss + final accumulate
// (finalize fused: mu/rinv computed inline from sum/sumsq)
__global__ void pair_reduce_kernel(const float* __restrict__ pairC, const float* __restrict__ G,
                                   const float* __restrict__ sum, const float* __restrict__ sumsq,
                                   float* __restrict__ out) {
    int p = blockIdx.x;
    int i = 0, rem = p;
    while (rem >= NH - 1 - i) { rem -= NH - 1 - i; ++i; }
    int j = i + 1 + rem;
    __shared__ float smui[DH], smuj[DH], sri[DH], srj[DH];
    {
        int t = threadIdx.x;
        int head = (t < DH) ? i : j;
        int d = t & (DH - 1);
        int c = head * DH + d;
        float m = sum[c] * (1.f / (float)N_TOK);
        float var = (sumsq[c] - (float)N_TOK * m * m) * (1.f / (float)(N_TOK - 1));
        var = fmaxf(var, 0.f);
        float r = 1.f / (sqrtf(var) + 1e-8f);
        if (t < DH) { smui[d] = m; sri[d] = r; }
        else        { smuj[d] = m; srj[d] = r; }
    }
    __syncthreads();
    const float invN = 1.f / (float)N_TOK;
    const float* pc = pairC + (size_t)p * (DH * DH);
    float s = 0.f;
    for (int idx = threadIdx.x; idx < DH * DH; idx += 256) {
        int d = idx >> 7, e = idx & 127;
        float cn = (pc[idx] * invN - smui[d] * smuj[e]) * sri[d] * srj[e];
        float diff = cn - ((d == e) ? 1.f : 0.f);
        s += diff * diff;
    }
    for (int o = 32; o; o >>= 1) s += __shfl_down(s, o);
    __shared__ float red[4];
    if ((threadIdx.x & 63) == 0) red[threadIdx.x >> 6] = s;
    __syncthreads();
    if (threadIdx.x == 0) {
        float t = red[0] + red[1] + red[2] + red[3];
        float x = -15.99f * (G[i * NH + j] - 0.0f);
        float sp = (x > 20.f) ? x : log1pf(expf(x));
        float wgt = 0.929f + (1.f - 0.929f) * sp;
        atomicAdd(out, wgt * t * (1.f / (float)NPAIRS));
    }
}

// ---------------------------------------------------------------- launcher
extern "C" void kernel_launch(void* const* d_in, const int* in_sizes, int n_in,
                              void* d_out, int out_size, void* d_ws, size_t ws_size,
                              hipStream_t stream) {
    const float* X = (const float*)d_in[0];
    const float* G = (const float*)d_in[1];
    float* out = (float*)d_out;
    char* ws = (char*)d_ws;

    float*         sum   = (float*)(ws + SUM_OFF);
    float*         sumsq = (float*)(ws + SUMSQ_OFF);
    float*         pairC = (float*)(ws + PC_OFF);
    unsigned char* Xt    = (unsigned char*)(ws + XT_OFF);

    hipMemsetAsync(ws + SUM_OFF, 0, 16384, stream);                     // sum+sumsq
    hipMemsetAsync(ws + PC_OFF, 0, (size_t)NPAIRS * DH * DH * 4, stream);
    hipMemsetAsync(d_out, 0, 4, stream);

    stats_transpose_kernel<<<dim3(16, 256), 256, 0, stream>>>(X, sum, sumsq, Xt);
    gram_kernel<<<dim3(KCHUNKS, NPAIRS), 256, 0, stream>>>(Xt, pairC);
    pair_reduce_kernel<<<NPAIRS, 256, 0, stream>>>(pairC, G, sum, sumsq, out);
}

// Round 5
// 245.882 us; speedup vs baseline: 1.3115x; 1.1725x over previous
//
#include <hip/hip_runtime.h>
#include <hip/hip_bf16.h>

// Problem constants
#define N_TOK   16384      // B*T
#define HDIM    2048       // H*d_h
#define NH      16
#define DH      128
#define NPAIRS  120
#define KCHUNKS 8
#define NKT     (N_TOK / 64)            // 256 k-tiles of 64 tokens
#define KT_PER_CHUNK (NKT / KCHUNKS)    // 32 (64-token panels per chunk)
#define KT128_PER_CHUNK (KT_PER_CHUNK / 2)  // 16 (128-token MX steps per chunk)
#define PANEL_BYTES 8192                // 128 c-rows x 64 tokens x 1B (fp8)

// Workspace layout (bytes) — total ~96.5 MB
#define SUM_OFF    0u
#define SUMSQ_OFF  8192u
#define PC_OFF     36864u                     // 8 kc-slabs x 120*128*128 f32 = 62,914,560 B
#define XT_OFF     62951424u                  // 2048*16384 fp8 = 33,554,432 B

typedef float f32x4 __attribute__((ext_vector_type(4)));
typedef int   v8i   __attribute__((ext_vector_type(8)));
typedef int   v2i   __attribute__((ext_vector_type(2)));
typedef long long i64t;

// ---------------------------------------------------------------- fp8 e4m3 pack
#if __has_builtin(__builtin_amdgcn_cvt_pk_fp8_f32)
__device__ __forceinline__ unsigned pk4_fp8(float a, float b, float c, float d) {
    int w = __builtin_amdgcn_cvt_pk_fp8_f32(a, b, 0, false);   // bytes 0,1
    w = __builtin_amdgcn_cvt_pk_fp8_f32(c, d, w, true);        // bytes 2,3
    return (unsigned)w;
}
#else
__device__ __forceinline__ unsigned char f2e4m3_sw(float f) {
    unsigned u = __float_as_uint(f);
    unsigned s = (u >> 24) & 0x80u;
    unsigned a = u & 0x7fffffffu;
    if (a >= 0x43e00000u) return (unsigned char)(s | 0x7eu);   // clamp to 448
    if (a < 0x3c800000u) {                                     // |x| < 2^-6: subnormal
        float av = __uint_as_float(a);
        int q = (int)rintf(av * 512.0f);                       // units of 2^-9
        return (unsigned char)(s | (unsigned)q);               // q==8 -> 0x08 == 2^-6 normal
    }
    unsigned lsb = (a >> 20) & 1u;
    a += 0x7ffffu + lsb;                                       // RNE to 3 mantissa bits
    int e8 = (int)(a >> 23) - 120;                             // -127 + 7
    unsigned m = (a >> 20) & 7u;
    return (unsigned char)(s | ((unsigned)e8 << 3) | m);
}
__device__ __forceinline__ unsigned pk4_fp8(float a, float b, float c, float d) {
    return (unsigned)f2e4m3_sw(a) | ((unsigned)f2e4m3_sw(b) << 8) |
           ((unsigned)f2e4m3_sw(c) << 16) | ((unsigned)f2e4m3_sw(d) << 24);
}
#endif

// ---------------------------------------------------------------- pass 1: fused stats + panelized transpose + fp8
// Block = one 8 KB panel: head h, tokens n0..n0+63, all 128 head-dims.
// Rows with (c>>3)&1 store their two 8B halves SWAPPED, so the gram kernel's
// LDS read swizzle can include r-bit-3 -> conflict-free ds_read_b64.
__global__ __launch_bounds__(256)
void stats_transpose_kernel(const float* __restrict__ X,
                            float* __restrict__ sum, float* __restrict__ sumsq,
                            unsigned char* __restrict__ Xt) {
    __shared__ float tile[64][129];               // stride 129
    __shared__ float sred[4][32][8];              // cross-wave stats partials
    const int h  = blockIdx.x;                    // 0..15
    const int by = blockIdx.y;                    // 0..255
    const int n0 = by * 64;
    const int tx = threadIdx.x;
    const int w  = tx >> 6, l = tx & 63;
    const int cq = tx & 31;                       // float4 index within 128-col slice
    const int rq0 = tx >> 5;                      // 0..7

    float4 s  = make_float4(0.f, 0.f, 0.f, 0.f);
    float4 ss = make_float4(0.f, 0.f, 0.f, 0.f);
    #pragma unroll
    for (int it = 0; it < 8; ++it) {
        int r = it * 8 + rq0;
        float4 x = *(const float4*)(X + (size_t)(n0 + r) * HDIM + h * DH + cq * 4);
        s.x += x.x; s.y += x.y; s.z += x.z; s.w += x.w;
        ss.x += x.x * x.x; ss.y += x.y * x.y; ss.z += x.z * x.z; ss.w += x.w * x.w;
        tile[r][cq * 4 + 0] = x.x; tile[r][cq * 4 + 1] = x.y;
        tile[r][cq * 4 + 2] = x.z; tile[r][cq * 4 + 3] = x.w;
    }
    s.x += __shfl_down(s.x, 32);  s.y += __shfl_down(s.y, 32);
    s.z += __shfl_down(s.z, 32);  s.w += __shfl_down(s.w, 32);
    ss.x += __shfl_down(ss.x, 32); ss.y += __shfl_down(ss.y, 32);
    ss.z += __shfl_down(ss.z, 32); ss.w += __shfl_down(ss.w, 32);
    if (l < 32) {
        sred[w][l][0] = s.x;  sred[w][l][1] = s.y;
        sred[w][l][2] = s.z;  sred[w][l][3] = s.w;
        sred[w][l][4] = ss.x; sred[w][l][5] = ss.y;
        sred[w][l][6] = ss.z; sred[w][l][7] = ss.w;
    }
    __syncthreads();
    if (tx < 32) {                                // wave 0 finishes stats
        float a0 = 0.f, a1 = 0.f, a2 = 0.f, a3 = 0.f;
        float b0 = 0.f, b1 = 0.f, b2 = 0.f, b3 = 0.f;
        #pragma unroll
        for (int w2 = 0; w2 < 4; ++w2) {
            a0 += sred[w2][tx][0]; a1 += sred[w2][tx][1];
            a2 += sred[w2][tx][2]; a3 += sred[w2][tx][3];
            b0 += sred[w2][tx][4]; b1 += sred[w2][tx][5];
            b2 += sred[w2][tx][6]; b3 += sred[w2][tx][7];
        }
        int c = h * DH + tx * 4;
        atomicAdd(&sum[c + 0], a0);  atomicAdd(&sum[c + 1], a1);
        atomicAdd(&sum[c + 2], a2);  atomicAdd(&sum[c + 3], a3);
        atomicAdd(&sumsq[c + 0], b0); atomicAdd(&sumsq[c + 1], b1);
        atomicAdd(&sumsq[c + 2], b2); atomicAdd(&sumsq[c + 3], b3);
    }
    // transpose write: 512 16B-chunks (one panel), contiguous per wave-instruction
    unsigned char* panel = Xt + ((size_t)h * NKT + by) * PANEL_BYTES;
    #pragma unroll
    for (int it = 0; it < 2; ++it) {
        int q = it * 256 + tx;
        int c = q >> 2, o = q & 3;                // chunk = (dim c, tokens 16o..16o+15)
        uint4 pk;
        pk.x = pk4_fp8(tile[o*16+ 0][c], tile[o*16+ 1][c], tile[o*16+ 2][c], tile[o*16+ 3][c]);
        pk.y = pk4_fp8(tile[o*16+ 4][c], tile[o*16+ 5][c], tile[o*16+ 6][c], tile[o*16+ 7][c]);
        pk.z = pk4_fp8(tile[o*16+ 8][c], tile[o*16+ 9][c], tile[o*16+10][c], tile[o*16+11][c]);
        pk.w = pk4_fp8(tile[o*16+12][c], tile[o*16+13][c], tile[o*16+14][c], tile[o*16+15][c]);
        // r-bit-3 half-swap: bakes the missing swizzle bit into the data so the
        // consumer's bank index depends on all 4 low row bits.
        uint4 outv = ((c >> 3) & 1) ? make_uint4(pk.z, pk.w, pk.x, pk.y) : pk;
        *(uint4*)(panel + c * 64 + o * 16) = outv;
    }
}

// ---------------------------------------------------------------- pass 3: pairwise raw Gram via MX-fp8 MFMA (K=128)
// 512-thread blocks: 8 waves in a 2x4 grid over the 128x128 tile -> per-wave
// 64x32 output (acc 4x2 f32x4 = 32 VGPR; ~100 VGPR total) -> 2 blocks/CU by
// LDS = 16 waves/CU = 4 waves/SIMD of TLP (vs 2 before). Double-buffered
// 2x32 KB LDS, 2-phase prefetch, one fused vmcnt+lgkm+barrier per step.
// Epilogue: plain stores to per-kc slab (no atomics).
__device__ __forceinline__ void gload16(const void* gsrc, void* ldst) {
    __builtin_amdgcn_global_load_lds(
        (const __attribute__((address_space(1))) unsigned int*)gsrc,
        (__attribute__((address_space(3))) unsigned int*)ldst,
        16, 0, 0);
}

// Register-resident gather: 4x ds_read_b64 -> v8i via constant-index inserts.
__device__ __forceinline__ v8i gather_frag(const unsigned char* rp,
                                           int o0, int o1, int o2, int o3) {
    v2i x0 = *(const v2i*)(rp + o0);
    v2i x1 = *(const v2i*)(rp + o1);
    v2i x2 = *(const v2i*)(rp + o2);
    v2i x3 = *(const v2i*)(rp + o3);
    v8i r;
    r[0] = x0[0]; r[1] = x0[1];
    r[2] = x1[0]; r[3] = x1[1];
    r[4] = x2[0]; r[5] = x2[1];
    r[6] = x3[0]; r[7] = x3[1];
    return r;
}

__global__ __launch_bounds__(512, 2)
void gram_kernel(const unsigned char* __restrict__ Xt, float* __restrict__ pairP) {
    const int kc = blockIdx.x;                    // K-chunk 0..7 -> XCD kc (linear%8)
    const int p  = blockIdx.y;                    // pair 0..119
    int i = 0, rem = p;
    while (rem >= NH - 1 - i) { rem -= NH - 1 - i; ++i; }
    const int j = i + 1 + rem;

    // double buffer: 2 x [A0|A1|B0|B1] = 64 KB -> 2 blocks/CU
    __shared__ alignas(16) unsigned char lds[2 * 4 * PANEL_BYTES];

    const int tx = threadIdx.x;
    const int w  = tx >> 6, l = tx & 63;
    const int wm = w >> 2, wn = w & 3;            // 2x4 wave grid over 128x128
    const int l15 = l & 15, quad = l >> 4;

    // Staging source swizzle (16B chunk level): cc = cl ^ ((r>>1)&3).
    // 512 threads cover one full 8 KB panel per gload16 issue.
    unsigned int goff;
    {
        int r0 = tx >> 2, cl0 = tx & 3;
        goff = (unsigned int)(r0 * 64 + (cl0 ^ ((r0 >> 1) & 3)) * 16);
    }
    const int lo = w * 1024;                      // wave-uniform LDS base
    const char* Abase = (const char*)Xt + ((size_t)i * NKT + (size_t)kc * KT_PER_CHUNK) * PANEL_BYTES;
    const char* Bbase = (const char*)Xt + ((size_t)j * NKT + (size_t)kc * KT_PER_CHUNK) * PANEL_BYTES;

    // stage one 128-token step (4 panels, 32 KB; 1 gload16 per panel per thread)
    auto STAGE = [&](int kt2, char* base) {
        const char* pa = Abase + (size_t)(kt2 * 2) * PANEL_BYTES;
        const char* pb = Bbase + (size_t)(kt2 * 2) * PANEL_BYTES;
        gload16(pa + goff,               base + lo);
        gload16(pa + PANEL_BYTES + goff, base + PANEL_BYTES + lo);
        gload16(pb + goff,               base + 2 * PANEL_BYTES + lo);
        gload16(pb + PANEL_BYTES + goff, base + 3 * PANEL_BYTES + lo);
    };

    f32x4 acc[4][2];
    #pragma unroll
    for (int mi = 0; mi < 4; ++mi)
        #pragma unroll
        for (int ni = 0; ni < 2; ++ni)
            acc[mi][ni] = (f32x4){0.f, 0.f, 0.f, 0.f};

    // Row-dependent unit swizzle (r == l15 mod 16 within a fragment)
    const int usw = (l15 & 6) | (l15 >> 3);
    const int selP = quad >> 1;                   // 64-token panel within the 128-step
    const int ub   = (quad & 1) * 4;              // logical 8B-unit base within panel
    const int puo0 = ((ub + 0) ^ usw) * 8;
    const int puo1 = ((ub + 1) ^ usw) * 8;
    const int puo2 = ((ub + 2) ^ usw) * 8;
    const int puo3 = ((ub + 3) ^ usw) * 8;
    const int offA = selP * PANEL_BYTES + (wm * 64 + l15) * 64;                   // + mi*1024
    const int offB = 2 * PANEL_BYTES + selP * PANEL_BYTES + (wn * 32 + l15) * 64; // + ni*1024

    // ---- prologue: stage step 0 into buf 0, drain, barrier
    STAGE(0, (char*)lds);
    asm volatile("s_waitcnt vmcnt(0)\n\ts_barrier" ::: "memory");

    int cur = 0;
    for (int kt = 0; kt < KT128_PER_CHUNK; ++kt) {
        // ---- prefetch next step into the other buffer
        if (kt + 1 < KT128_PER_CHUNK)
            STAGE(kt + 1, (char*)lds + (cur ^ 1) * (4 * PANEL_BYTES));

        // ---- compute current buffer
        const unsigned char* bufb = lds + cur * (4 * PANEL_BYTES);
        const unsigned char* laP = bufb + offA;
        const unsigned char* lbP = bufb + offB;

        v8i a0 = gather_frag(laP + 0 * 1024, puo0, puo1, puo2, puo3);
        v8i a1 = gather_frag(laP + 1 * 1024, puo0, puo1, puo2, puo3);
        v8i a2 = gather_frag(laP + 2 * 1024, puo0, puo1, puo2, puo3);
        v8i a3 = gather_frag(laP + 3 * 1024, puo0, puo1, puo2, puo3);
        #pragma unroll
        for (int ni = 0; ni < 2; ++ni) {
            v8i b = gather_frag(lbP + ni * 1024, puo0, puo1, puo2, puo3);
            acc[0][ni] = __builtin_amdgcn_mfma_scale_f32_16x16x128_f8f6f4(
                a0, b, acc[0][ni], 0, 0, 0, 0x7F7F7F7F, 0, 0x7F7F7F7F);
            acc[1][ni] = __builtin_amdgcn_mfma_scale_f32_16x16x128_f8f6f4(
                a1, b, acc[1][ni], 0, 0, 0, 0x7F7F7F7F, 0, 0x7F7F7F7F);
            acc[2][ni] = __builtin_amdgcn_mfma_scale_f32_16x16x128_f8f6f4(
                a2, b, acc[2][ni], 0, 0, 0, 0x7F7F7F7F, 0, 0x7F7F7F7F);
            acc[3][ni] = __builtin_amdgcn_mfma_scale_f32_16x16x128_f8f6f4(
                a3, b, acc[3][ni], 0, 0, 0, 0x7F7F7F7F, 0, 0x7F7F7F7F);
        }

        // ---- end-of-iter: prefetched loads landed (latency hidden by MFMA),
        //      our ds_reads retired, one barrier.
        if (kt + 1 < KT128_PER_CHUNK)
            asm volatile("s_waitcnt vmcnt(0) lgkmcnt(0)\n\ts_barrier" ::: "memory");
        cur ^= 1;
    }

    // Epilogue: plain stores into this kc's slab (no atomics, no contention)
    float* pc = pairP + ((size_t)kc * NPAIRS + (size_t)p) * (DH * DH);
    #pragma unroll
    for (int mi = 0; mi < 4; ++mi)
        #pragma unroll
        for (int ni = 0; ni < 2; ++ni)
            #pragma unroll
            for (int r = 0; r < 4; ++r) {
                int row = wm * 64 + mi * 16 + quad * 4 + r;  // d (head-i dim)
                int col = wn * 32 + ni * 16 + l15;           // e (head-j dim)
                pc[row * DH + col] = acc[mi][ni][r];
            }
}

// ---------------------------------------------------------------- pass 4: per-pair loss + final accumulate
// Sums the 8 kc-slabs (float4-vectorized), normalizes, reduces.
__global__ void pair_reduce_kernel(const float* __restrict__ pairP, const float* __restrict__ G,
                                   const float* __restrict__ sum, const float* __restrict__ sumsq,
                                   float* __restrict__ out) {
    int p = blockIdx.x;
    int i = 0, rem = p;
    while (rem >= NH - 1 - i) { rem -= NH - 1 - i; ++i; }
    int j = i + 1 + rem;
    __shared__ float smui[DH], smuj[DH], sri[DH], srj[DH];
    {
        int t = threadIdx.x;
        int head = (t < DH) ? i : j;
        int d = t & (DH - 1);
        int c = head * DH + d;
        float m = sum[c] * (1.f / (float)N_TOK);
        float var = (sumsq[c] - (float)N_TOK * m * m) * (1.f / (float)(N_TOK - 1));
        var = fmaxf(var, 0.f);
        float r = 1.f / (sqrtf(var) + 1e-8f);
        if (t < DH) { smui[d] = m; sri[d] = r; }
        else        { smuj[d] = m; srj[d] = r; }
    }
    __syncthreads();
    const float invN = 1.f / (float)N_TOK;
    const size_t SLAB = (size_t)NPAIRS * DH * DH;     // floats per kc slab
    const float* base = pairP + (size_t)p * (DH * DH);
    float s = 0.f;
    for (int q = threadIdx.x; q < (DH * DH) / 4; q += 256) {
        float4 v = ((const float4*)base)[q];
        #pragma unroll
        for (int kc = 1; kc < KCHUNKS; ++kc) {
            float4 t = ((const float4*)(base + kc * SLAB))[q];
            v.x += t.x; v.y += t.y; v.z += t.z; v.w += t.w;
        }
        int d = q >> 5;                // 32 float4 per 128-col row
        int e0 = (q & 31) * 4;
        float md = smui[d], rd = sri[d];
        float cn, df;
        cn = (v.x * invN - md * smuj[e0 + 0]) * rd * srj[e0 + 0];
        df = cn - ((d == e0 + 0) ? 1.f : 0.f); s += df * df;
        cn = (v.y * invN - md * smuj[e0 + 1]) * rd * srj[e0 + 1];
        df = cn - ((d == e0 + 1) ? 1.f : 0.f); s += df * df;
        cn = (v.z * invN - md * smuj[e0 + 2]) * rd * srj[e0 + 2];
        df = cn - ((d == e0 + 2) ? 1.f : 0.f); s += df * df;
        cn = (v.w * invN - md * smuj[e0 + 3]) * rd * srj[e0 + 3];
        df = cn - ((d == e0 + 3) ? 1.f : 0.f); s += df * df;
    }
    for (int o = 32; o; o >>= 1) s += __shfl_down(s, o);
    __shared__ float red[4];
    if ((threadIdx.x & 63) == 0) red[threadIdx.x >> 6] = s;
    __syncthreads();
    if (threadIdx.x == 0) {
        float t = red[0] + red[1] + red[2] + red[3];
        float x = -15.99f * (G[i * NH + j] - 0.0f);
        float sp = (x > 20.f) ? x : log1pf(expf(x));
        float wgt = 0.929f + (1.f - 0.929f) * sp;
        atomicAdd(out, wgt * t * (1.f / (float)NPAIRS));
    }
}

// ---------------------------------------------------------------- launcher
extern "C" void kernel_launch(void* const* d_in, const int* in_sizes, int n_in,
                              void* d_out, int out_size, void* d_ws, size_t ws_size,
                              hipStream_t stream) {
    const float* X = (const float*)d_in[0];
    const float* G = (const float*)d_in[1];
    float* out = (float*)d_out;
    char* ws = (char*)d_ws;

    float*         sum   = (float*)(ws + SUM_OFF);
    float*         sumsq = (float*)(ws + SUMSQ_OFF);
    float*         pairP = (float*)(ws + PC_OFF);
    unsigned char* Xt    = (unsigned char*)(ws + XT_OFF);

    hipMemsetAsync(ws + SUM_OFF, 0, 16384, stream);                     // sum+sumsq
    hipMemsetAsync(d_out, 0, 4, stream);

    stats_transpose_kernel<<<dim3(16, 256), 256, 0, stream>>>(X, sum, sumsq, Xt);
    gram_kernel<<<dim3(KCHUNKS, NPAIRS), 512, 0, stream>>>(Xt, pairP);
    pair_reduce_kernel<<<NPAIRS, 256, 0, stream>>>(pairP, G, sum, sumsq, out);
}

// Round 7
// 243.103 us; speedup vs baseline: 1.3265x; 1.0114x over previous
//
#include <hip/hip_runtime.h>
#include <hip/hip_bf16.h>

// Problem constants
#define N_TOK   16384      // B*T
#define HDIM    2048       // H*d_h
#define NH      16
#define DH      128
#define NPAIRS  120
#define KCHUNKS 4          // 4 chunks: 480 blocks = same 32-step makespan as 8,
                           // but HALF the slab write+read traffic   // <- r6 change
#define NKT     (N_TOK / 64)            // 256 k-tiles of 64 tokens
#define KT_PER_CHUNK (NKT / KCHUNKS)    // 64 (64-token panels per chunk)
#define KT128_PER_CHUNK (KT_PER_CHUNK / 2)  // 32 (128-token MX steps per chunk)
#define PANEL_BYTES 8192                // 128 c-rows x 64 tokens x 1B (fp8)

// Workspace layout (bytes) — total ~65 MB
#define SUM_OFF    0u
#define SUMSQ_OFF  8192u
#define PC_OFF     36864u                     // 4 kc-slabs x 120*128*128 f32 = 31,457,280 B
#define XT_OFF     31494144u                  // 2048*16384 fp8 = 33,554,432 B

typedef float f32x4 __attribute__((ext_vector_type(4)));
typedef int   v8i   __attribute__((ext_vector_type(8)));
typedef int   v2i   __attribute__((ext_vector_type(2)));
typedef long long i64t;

// ---------------------------------------------------------------- fp8 e4m3 pack
#if __has_builtin(__builtin_amdgcn_cvt_pk_fp8_f32)
__device__ __forceinline__ unsigned pk4_fp8(float a, float b, float c, float d) {
    int w = __builtin_amdgcn_cvt_pk_fp8_f32(a, b, 0, false);   // bytes 0,1
    w = __builtin_amdgcn_cvt_pk_fp8_f32(c, d, w, true);        // bytes 2,3
    return (unsigned)w;
}
#else
__device__ __forceinline__ unsigned char f2e4m3_sw(float f) {
    unsigned u = __float_as_uint(f);
    unsigned s = (u >> 24) & 0x80u;
    unsigned a = u & 0x7fffffffu;
    if (a >= 0x43e00000u) return (unsigned char)(s | 0x7eu);   // clamp to 448
    if (a < 0x3c800000u) {                                     // |x| < 2^-6: subnormal
        float av = __uint_as_float(a);
        int q = (int)rintf(av * 512.0f);                       // units of 2^-9
        return (unsigned char)(s | (unsigned)q);               // q==8 -> 0x08 == 2^-6 normal
    }
    unsigned lsb = (a >> 20) & 1u;
    a += 0x7ffffu + lsb;                                       // RNE to 3 mantissa bits
    int e8 = (int)(a >> 23) - 120;                             // -127 + 7
    unsigned m = (a >> 20) & 7u;
    return (unsigned char)(s | ((unsigned)e8 << 3) | m);
}
__device__ __forceinline__ unsigned pk4_fp8(float a, float b, float c, float d) {
    return (unsigned)f2e4m3_sw(a) | ((unsigned)f2e4m3_sw(b) << 8) |
           ((unsigned)f2e4m3_sw(c) << 16) | ((unsigned)f2e4m3_sw(d) << 24);
}
#endif

// ---------------------------------------------------------------- pass 1: fused stats + panelized transpose + fp8
// Block = one 8 KB panel: head h, tokens n0..n0+63, all 128 head-dims.
// Rows with (c>>3)&1 store their two 8B halves SWAPPED, so the gram kernel's
// LDS read swizzle can include r-bit-3 -> conflict-free ds_read_b64.
__global__ __launch_bounds__(256)
void stats_transpose_kernel(const float* __restrict__ X,
                            float* __restrict__ sum, float* __restrict__ sumsq,
                            unsigned char* __restrict__ Xt) {
    __shared__ float tile[64][129];               // stride 129
    __shared__ float sred[4][32][8];              // cross-wave stats partials
    const int h  = blockIdx.x;                    // 0..15
    const int by = blockIdx.y;                    // 0..255
    const int n0 = by * 64;
    const int tx = threadIdx.x;
    const int w  = tx >> 6, l = tx & 63;
    const int cq = tx & 31;                       // float4 index within 128-col slice
    const int rq0 = tx >> 5;                      // 0..7

    float4 s  = make_float4(0.f, 0.f, 0.f, 0.f);
    float4 ss = make_float4(0.f, 0.f, 0.f, 0.f);
    #pragma unroll
    for (int it = 0; it < 8; ++it) {
        int r = it * 8 + rq0;
        float4 x = *(const float4*)(X + (size_t)(n0 + r) * HDIM + h * DH + cq * 4);
        s.x += x.x; s.y += x.y; s.z += x.z; s.w += x.w;
        ss.x += x.x * x.x; ss.y += x.y * x.y; ss.z += x.z * x.z; ss.w += x.w * x.w;
        tile[r][cq * 4 + 0] = x.x; tile[r][cq * 4 + 1] = x.y;
        tile[r][cq * 4 + 2] = x.z; tile[r][cq * 4 + 3] = x.w;
    }
    s.x += __shfl_down(s.x, 32);  s.y += __shfl_down(s.y, 32);
    s.z += __shfl_down(s.z, 32);  s.w += __shfl_down(s.w, 32);
    ss.x += __shfl_down(ss.x, 32); ss.y += __shfl_down(ss.y, 32);
    ss.z += __shfl_down(ss.z, 32); ss.w += __shfl_down(ss.w, 32);
    if (l < 32) {
        sred[w][l][0] = s.x;  sred[w][l][1] = s.y;
        sred[w][l][2] = s.z;  sred[w][l][3] = s.w;
        sred[w][l][4] = ss.x; sred[w][l][5] = ss.y;
        sred[w][l][6] = ss.z; sred[w][l][7] = ss.w;
    }
    __syncthreads();
    if (tx < 32) {                                // wave 0 finishes stats
        float a0 = 0.f, a1 = 0.f, a2 = 0.f, a3 = 0.f;
        float b0 = 0.f, b1 = 0.f, b2 = 0.f, b3 = 0.f;
        #pragma unroll
        for (int w2 = 0; w2 < 4; ++w2) {
            a0 += sred[w2][tx][0]; a1 += sred[w2][tx][1];
            a2 += sred[w2][tx][2]; a3 += sred[w2][tx][3];
            b0 += sred[w2][tx][4]; b1 += sred[w2][tx][5];
            b2 += sred[w2][tx][6]; b3 += sred[w2][tx][7];
        }
        int c = h * DH + tx * 4;
        atomicAdd(&sum[c + 0], a0);  atomicAdd(&sum[c + 1], a1);
        atomicAdd(&sum[c + 2], a2);  atomicAdd(&sum[c + 3], a3);
        atomicAdd(&sumsq[c + 0], b0); atomicAdd(&sumsq[c + 1], b1);
        atomicAdd(&sumsq[c + 2], b2); atomicAdd(&sumsq[c + 3], b3);
    }
    // transpose write: 512 16B-chunks (one panel), contiguous per wave-instruction
    unsigned char* panel = Xt + ((size_t)h * NKT + by) * PANEL_BYTES;
    #pragma unroll
    for (int it = 0; it < 2; ++it) {
        int q = it * 256 + tx;
        int c = q >> 2, o = q & 3;                // chunk = (dim c, tokens 16o..16o+15)
        uint4 pk;
        pk.x = pk4_fp8(tile[o*16+ 0][c], tile[o*16+ 1][c], tile[o*16+ 2][c], tile[o*16+ 3][c]);
        pk.y = pk4_fp8(tile[o*16+ 4][c], tile[o*16+ 5][c], tile[o*16+ 6][c], tile[o*16+ 7][c]);
        pk.z = pk4_fp8(tile[o*16+ 8][c], tile[o*16+ 9][c], tile[o*16+10][c], tile[o*16+11][c]);
        pk.w = pk4_fp8(tile[o*16+12][c], tile[o*16+13][c], tile[o*16+14][c], tile[o*16+15][c]);
        // r-bit-3 half-swap: bakes the missing swizzle bit into the data so the
        // consumer's bank index depends on all 4 low row bits.
        uint4 outv = ((c >> 3) & 1) ? make_uint4(pk.z, pk.w, pk.x, pk.y) : pk;
        *(uint4*)(panel + c * 64 + o * 16) = outv;
    }
}

// ---------------------------------------------------------------- pass 3: pairwise raw Gram via MX-fp8 MFMA (K=128)
// 512-thread blocks: 8 waves in a 2x4 grid over the 128x128 tile -> per-wave
// 64x32 output -> 2 blocks/CU (LDS 64 KB) = 4 waves/SIMD TLP. Double-buffered
// 2x32 KB LDS, 2-phase prefetch, one fused vmcnt+lgkm+barrier per step.
// setprio(1) around the compute cluster (T5): the two resident blocks run
// phase-staggered -> scheduler favors the MFMA-entering waves.
// Epilogue: plain stores to per-kc slab (no atomics).
__device__ __forceinline__ void gload16(const void* gsrc, void* ldst) {
    __builtin_amdgcn_global_load_lds(
        (const __attribute__((address_space(1))) unsigned int*)gsrc,
        (__attribute__((address_space(3))) unsigned int*)ldst,
        16, 0, 0);
}

// Register-resident gather: 4x ds_read_b64 -> v8i via constant-index inserts.
__device__ __forceinline__ v8i gather_frag(const unsigned char* rp,
                                           int o0, int o1, int o2, int o3) {
    v2i x0 = *(const v2i*)(rp + o0);
    v2i x1 = *(const v2i*)(rp + o1);
    v2i x2 = *(const v2i*)(rp + o2);
    v2i x3 = *(const v2i*)(rp + o3);
    v8i r;
    r[0] = x0[0]; r[1] = x0[1];
    r[2] = x1[0]; r[3] = x1[1];
    r[4] = x2[0]; r[5] = x2[1];
    r[6] = x3[0]; r[7] = x3[1];
    return r;
}

__global__ __launch_bounds__(512, 2)
void gram_kernel(const unsigned char* __restrict__ Xt, float* __restrict__ pairP) {
    const int kc = blockIdx.x;                    // K-chunk 0..3
    const int p  = blockIdx.y;                    // pair 0..119
    int i = 0, rem = p;
    while (rem >= NH - 1 - i) { rem -= NH - 1 - i; ++i; }
    const int j = i + 1 + rem;

    // double buffer: 2 x [A0|A1|B0|B1] = 64 KB -> 2 blocks/CU
    __shared__ alignas(16) unsigned char lds[2 * 4 * PANEL_BYTES];

    const int tx = threadIdx.x;
    const int w  = tx >> 6, l = tx & 63;
    const int wm = w >> 2, wn = w & 3;            // 2x4 wave grid over 128x128
    const int l15 = l & 15, quad = l >> 4;

    // Staging source swizzle (16B chunk level): cc = cl ^ ((r>>1)&3).
    // 512 threads cover one full 8 KB panel per gload16 issue.
    unsigned int goff;
    {
        int r0 = tx >> 2, cl0 = tx & 3;
        goff = (unsigned int)(r0 * 64 + (cl0 ^ ((r0 >> 1) & 3)) * 16);
    }
    const int lo = w * 1024;                      // wave-uniform LDS base
    const char* Abase = (const char*)Xt + ((size_t)i * NKT + (size_t)kc * KT_PER_CHUNK) * PANEL_BYTES;
    const char* Bbase = (const char*)Xt + ((size_t)j * NKT + (size_t)kc * KT_PER_CHUNK) * PANEL_BYTES;

    // stage one 128-token step (4 panels, 32 KB; 1 gload16 per panel per thread)
    auto STAGE = [&](int kt2, char* base) {
        const char* pa = Abase + (size_t)(kt2 * 2) * PANEL_BYTES;
        const char* pb = Bbase + (size_t)(kt2 * 2) * PANEL_BYTES;
        gload16(pa + goff,               base + lo);
        gload16(pa + PANEL_BYTES + goff, base + PANEL_BYTES + lo);
        gload16(pb + goff,               base + 2 * PANEL_BYTES + lo);
        gload16(pb + PANEL_BYTES + goff, base + 3 * PANEL_BYTES + lo);
    };

    f32x4 acc[4][2];
    #pragma unroll
    for (int mi = 0; mi < 4; ++mi)
        #pragma unroll
        for (int ni = 0; ni < 2; ++ni)
            acc[mi][ni] = (f32x4){0.f, 0.f, 0.f, 0.f};

    // Row-dependent unit swizzle (r == l15 mod 16 within a fragment)
    const int usw = (l15 & 6) | (l15 >> 3);
    const int selP = quad >> 1;                   // 64-token panel within the 128-step
    const int ub   = (quad & 1) * 4;              // logical 8B-unit base within panel
    const int puo0 = ((ub + 0) ^ usw) * 8;
    const int puo1 = ((ub + 1) ^ usw) * 8;
    const int puo2 = ((ub + 2) ^ usw) * 8;
    const int puo3 = ((ub + 3) ^ usw) * 8;
    const int offA = selP * PANEL_BYTES + (wm * 64 + l15) * 64;                   // + mi*1024
    const int offB = 2 * PANEL_BYTES + selP * PANEL_BYTES + (wn * 32 + l15) * 64; // + ni*1024

    // ---- prologue: stage step 0 into buf 0, drain, barrier
    STAGE(0, (char*)lds);
    asm volatile("s_waitcnt vmcnt(0)\n\ts_barrier" ::: "memory");

    int cur = 0;
    for (int kt = 0; kt < KT128_PER_CHUNK; ++kt) {
        // ---- prefetch next step into the other buffer
        if (kt + 1 < KT128_PER_CHUNK)
            STAGE(kt + 1, (char*)lds + (cur ^ 1) * (4 * PANEL_BYTES));

        // ---- compute current buffer
        const unsigned char* bufb = lds + cur * (4 * PANEL_BYTES);
        const unsigned char* laP = bufb + offA;
        const unsigned char* lbP = bufb + offB;

        __builtin_amdgcn_s_setprio(1);
        v8i a0 = gather_frag(laP + 0 * 1024, puo0, puo1, puo2, puo3);
        v8i a1 = gather_frag(laP + 1 * 1024, puo0, puo1, puo2, puo3);
        v8i a2 = gather_frag(laP + 2 * 1024, puo0, puo1, puo2, puo3);
        v8i a3 = gather_frag(laP + 3 * 1024, puo0, puo1, puo2, puo3);
        #pragma unroll
        for (int ni = 0; ni < 2; ++ni) {
            v8i b = gather_frag(lbP + ni * 1024, puo0, puo1, puo2, puo3);
            acc[0][ni] = __builtin_amdgcn_mfma_scale_f32_16x16x128_f8f6f4(
                a0, b, acc[0][ni], 0, 0, 0, 0x7F7F7F7F, 0, 0x7F7F7F7F);
            acc[1][ni] = __builtin_amdgcn_mfma_scale_f32_16x16x128_f8f6f4(
                a1, b, acc[1][ni], 0, 0, 0, 0x7F7F7F7F, 0, 0x7F7F7F7F);
            acc[2][ni] = __builtin_amdgcn_mfma_scale_f32_16x16x128_f8f6f4(
                a2, b, acc[2][ni], 0, 0, 0, 0x7F7F7F7F, 0, 0x7F7F7F7F);
            acc[3][ni] = __builtin_amdgcn_mfma_scale_f32_16x16x128_f8f6f4(
                a3, b, acc[3][ni], 0, 0, 0, 0x7F7F7F7F, 0, 0x7F7F7F7F);
        }
        __builtin_amdgcn_s_setprio(0);

        // ---- end-of-iter: prefetched loads landed (latency hidden by MFMA),
        //      our ds_reads retired, one barrier.
        if (kt + 1 < KT128_PER_CHUNK)
            asm volatile("s_waitcnt vmcnt(0) lgkmcnt(0)\n\ts_barrier" ::: "memory");
        cur ^= 1;
    }

    // Epilogue: plain stores into this kc's slab (no atomics, no contention)
    float* pc = pairP + ((size_t)kc * NPAIRS + (size_t)p) * (DH * DH);
    #pragma unroll
    for (int mi = 0; mi < 4; ++mi)
        #pragma unroll
        for (int ni = 0; ni < 2; ++ni)
            #pragma unroll
            for (int r = 0; r < 4; ++r) {
                int row = wm * 64 + mi * 16 + quad * 4 + r;  // d (head-i dim)
                int col = wn * 32 + ni * 16 + l15;           // e (head-j dim)
                pc[row * DH + col] = acc[mi][ni][r];
            }
}

// ---------------------------------------------------------------- pass 4: per-pair loss + final accumulate
// Sums the kc-slabs (float4-vectorized), normalizes, reduces.
__global__ void pair_reduce_kernel(const float* __restrict__ pairP, const float* __restrict__ G,
                                   const float* __restrict__ sum, const float* __restrict__ sumsq,
                                   float* __restrict__ out) {
    int p = blockIdx.x;
    int i = 0, rem = p;
    while (rem >= NH - 1 - i) { rem -= NH - 1 - i; ++i; }
    int j = i + 1 + rem;
    __shared__ float smui[DH], smuj[DH], sri[DH], srj[DH];
    {
        int t = threadIdx.x;
        int head = (t < DH) ? i : j;
        int d = t & (DH - 1);
        int c = head * DH + d;
        float m = sum[c] * (1.f / (float)N_TOK);
        float var = (sumsq[c] - (float)N_TOK * m * m) * (1.f / (float)(N_TOK - 1));
        var = fmaxf(var, 0.f);
        float r = 1.f / (sqrtf(var) + 1e-8f);
        if (t < DH) { smui[d] = m; sri[d] = r; }
        else        { smuj[d] = m; srj[d] = r; }
    }
    __syncthreads();
    const float invN = 1.f / (float)N_TOK;
    const size_t SLAB = (size_t)NPAIRS * DH * DH;     // floats per kc slab
    const float* base = pairP + (size_t)p * (DH * DH);
    float s = 0.f;
    for (int q = threadIdx.x; q < (DH * DH) / 4; q += 256) {
        float4 v = ((const float4*)base)[q];
        #pragma unroll
        for (int kc = 1; kc < KCHUNKS; ++kc) {
            float4 t = ((const float4*)(base + kc * SLAB))[q];
            v.x += t.x; v.y += t.y; v.z += t.z; v.w += t.w;
        }
        int d = q >> 5;                // 32 float4 per 128-col row
        int e0 = (q & 31) * 4;
        float md = smui[d], rd = sri[d];
        float cn, df;
        cn = (v.x * invN - md * smuj[e0 + 0]) * rd * srj[e0 + 0];
        df = cn - ((d == e0 + 0) ? 1.f : 0.f); s += df * df;
        cn = (v.y * invN - md * smuj[e0 + 1]) * rd * srj[e0 + 1];
        df = cn - ((d == e0 + 1) ? 1.f : 0.f); s += df * df;
        cn = (v.z * invN - md * smuj[e0 + 2]) * rd * srj[e0 + 2];
        df = cn - ((d == e0 + 2) ? 1.f : 0.f); s += df * df;
        cn = (v.w * invN - md * smuj[e0 + 3]) * rd * srj[e0 + 3];
        df = cn - ((d == e0 + 3) ? 1.f : 0.f); s += df * df;
    }
    for (int o = 32; o; o >>= 1) s += __shfl_down(s, o);
    __shared__ float red[4];
    if ((threadIdx.x & 63) == 0) red[threadIdx.x >> 6] = s;
    __syncthreads();
    if (threadIdx.x == 0) {
        float t = red[0] + red[1] + red[2] + red[3];
        float x = -15.99f * (G[i * NH + j] - 0.0f);
        float sp = (x > 20.f) ? x : log1pf(expf(x));
        float wgt = 0.929f + (1.f - 0.929f) * sp;
        atomicAdd(out, wgt * t * (1.f / (float)NPAIRS));
    }
}

// ---------------------------------------------------------------- launcher
extern "C" void kernel_launch(void* const* d_in, const int* in_sizes, int n_in,
                              void* d_out, int out_size, void* d_ws, size_t ws_size,
                              hipStream_t stream) {
    const float* X = (const float*)d_in[0];
    const float* G = (const float*)d_in[1];
    float* out = (float*)d_out;
    char* ws = (char*)d_ws;

    float*         sum   = (float*)(ws + SUM_OFF);
    float*         sumsq = (float*)(ws + SUMSQ_OFF);
    float*         pairP = (float*)(ws + PC_OFF);
    unsigned char* Xt    = (unsigned char*)(ws + XT_OFF);

    hipMemsetAsync(ws + SUM_OFF, 0, 16384, stream);                     // sum+sumsq
    hipMemsetAsync(d_out, 0, 4, stream);

    stats_transpose_kernel<<<dim3(16, 256), 256, 0, stream>>>(X, sum, sumsq, Xt);
    gram_kernel<<<dim3(KCHUNKS, NPAIRS), 512, 0, stream>>>(Xt, pairP);
    pair_reduce_kernel<<<NPAIRS, 256, 0, stream>>>(pairP, G, sum, sumsq, out);
}

// Round 8
// 239.918 us; speedup vs baseline: 1.3441x; 1.0133x over previous
//
#include <hip/hip_runtime.h>
#include <hip/hip_bf16.h>

// Problem constants
#define N_TOK   16384      // B*T
#define HDIM    2048       // H*d_h
#define NH      16
#define DH      128
#define NPAIRS  120
#define KCHUNKS 4
#define NKT     (N_TOK / 64)            // 256 k-tiles of 64 tokens
#define KT_PER_CHUNK (NKT / KCHUNKS)    // 64 (64-token panels per chunk)
#define SKT     KT_PER_CHUNK            // panel-steps per gram block
#define PANEL_BYTES 8192                // 128 c-rows x 64 tokens x 1B (fp8)

// Workspace layout (bytes) — total ~65 MB
#define SUM_OFF    0u
#define SUMSQ_OFF  8192u
#define PC_OFF     36864u                     // 4 kc-slabs x 120*128*128 f32 = 31,457,280 B
#define XT_OFF     31494144u                  // 2048*16384 fp8 = 33,554,432 B

typedef float f32x4  __attribute__((ext_vector_type(4)));
typedef float f32x16 __attribute__((ext_vector_type(16)));
typedef int   v8i    __attribute__((ext_vector_type(8)));
typedef int   v2i    __attribute__((ext_vector_type(2)));
typedef long long i64t;

// ---------------------------------------------------------------- fp8 e4m3 pack
#if __has_builtin(__builtin_amdgcn_cvt_pk_fp8_f32)
__device__ __forceinline__ unsigned pk4_fp8(float a, float b, float c, float d) {
    int w = __builtin_amdgcn_cvt_pk_fp8_f32(a, b, 0, false);   // bytes 0,1
    w = __builtin_amdgcn_cvt_pk_fp8_f32(c, d, w, true);        // bytes 2,3
    return (unsigned)w;
}
#else
__device__ __forceinline__ unsigned char f2e4m3_sw(float f) {
    unsigned u = __float_as_uint(f);
    unsigned s = (u >> 24) & 0x80u;
    unsigned a = u & 0x7fffffffu;
    if (a >= 0x43e00000u) return (unsigned char)(s | 0x7eu);   // clamp to 448
    if (a < 0x3c800000u) {                                     // |x| < 2^-6: subnormal
        float av = __uint_as_float(a);
        int q = (int)rintf(av * 512.0f);                       // units of 2^-9
        return (unsigned char)(s | (unsigned)q);               // q==8 -> 0x08 == 2^-6 normal
    }
    unsigned lsb = (a >> 20) & 1u;
    a += 0x7ffffu + lsb;                                       // RNE to 3 mantissa bits
    int e8 = (int)(a >> 23) - 120;                             // -127 + 7
    unsigned m = (a >> 20) & 7u;
    return (unsigned char)(s | ((unsigned)e8 << 3) | m);
}
__device__ __forceinline__ unsigned pk4_fp8(float a, float b, float c, float d) {
    return (unsigned)f2e4m3_sw(a) | ((unsigned)f2e4m3_sw(b) << 8) |
           ((unsigned)f2e4m3_sw(c) << 16) | ((unsigned)f2e4m3_sw(d) << 24);
}
#endif

// ---------------------------------------------------------------- pass 1: fused stats + panelized transpose + fp8
// Block = one 8 KB panel: head h, tokens n0..n0+63, all 128 head-dims.
// Rows with (c>>3)&1 store their two 8B halves SWAPPED, so the gram kernel's
// LDS read swizzle can include r-bit-3 -> near-conflict-free ds_read_b64.
__global__ __launch_bounds__(256)
void stats_transpose_kernel(const float* __restrict__ X,
                            float* __restrict__ sum, float* __restrict__ sumsq,
                            unsigned char* __restrict__ Xt) {
    __shared__ float tile[64][129];               // stride 129
    __shared__ float sred[4][32][8];              // cross-wave stats partials
    const int h  = blockIdx.x;                    // 0..15
    const int by = blockIdx.y;                    // 0..255
    const int n0 = by * 64;
    const int tx = threadIdx.x;
    const int w  = tx >> 6, l = tx & 63;
    const int cq = tx & 31;                       // float4 index within 128-col slice
    const int rq0 = tx >> 5;                      // 0..7

    float4 s  = make_float4(0.f, 0.f, 0.f, 0.f);
    float4 ss = make_float4(0.f, 0.f, 0.f, 0.f);
    #pragma unroll
    for (int it = 0; it < 8; ++it) {
        int r = it * 8 + rq0;
        float4 x = *(const float4*)(X + (size_t)(n0 + r) * HDIM + h * DH + cq * 4);
        s.x += x.x; s.y += x.y; s.z += x.z; s.w += x.w;
        ss.x += x.x * x.x; ss.y += x.y * x.y; ss.z += x.z * x.z; ss.w += x.w * x.w;
        tile[r][cq * 4 + 0] = x.x; tile[r][cq * 4 + 1] = x.y;
        tile[r][cq * 4 + 2] = x.z; tile[r][cq * 4 + 3] = x.w;
    }
    s.x += __shfl_down(s.x, 32);  s.y += __shfl_down(s.y, 32);
    s.z += __shfl_down(s.z, 32);  s.w += __shfl_down(s.w, 32);
    ss.x += __shfl_down(ss.x, 32); ss.y += __shfl_down(ss.y, 32);
    ss.z += __shfl_down(ss.z, 32); ss.w += __shfl_down(ss.w, 32);
    if (l < 32) {
        sred[w][l][0] = s.x;  sred[w][l][1] = s.y;
        sred[w][l][2] = s.z;  sred[w][l][3] = s.w;
        sred[w][l][4] = ss.x; sred[w][l][5] = ss.y;
        sred[w][l][6] = ss.z; sred[w][l][7] = ss.w;
    }
    __syncthreads();
    if (tx < 32) {                                // wave 0 finishes stats
        float a0 = 0.f, a1 = 0.f, a2 = 0.f, a3 = 0.f;
        float b0 = 0.f, b1 = 0.f, b2 = 0.f, b3 = 0.f;
        #pragma unroll
        for (int w2 = 0; w2 < 4; ++w2) {
            a0 += sred[w2][tx][0]; a1 += sred[w2][tx][1];
            a2 += sred[w2][tx][2]; a3 += sred[w2][tx][3];
            b0 += sred[w2][tx][4]; b1 += sred[w2][tx][5];
            b2 += sred[w2][tx][6]; b3 += sred[w2][tx][7];
        }
        int c = h * DH + tx * 4;
        atomicAdd(&sum[c + 0], a0);  atomicAdd(&sum[c + 1], a1);
        atomicAdd(&sum[c + 2], a2);  atomicAdd(&sum[c + 3], a3);
        atomicAdd(&sumsq[c + 0], b0); atomicAdd(&sumsq[c + 1], b1);
        atomicAdd(&sumsq[c + 2], b2); atomicAdd(&sumsq[c + 3], b3);
    }
    // transpose write: 512 16B-chunks (one panel), contiguous per wave-instruction
    unsigned char* panel = Xt + ((size_t)h * NKT + by) * PANEL_BYTES;
    #pragma unroll
    for (int it = 0; it < 2; ++it) {
        int q = it * 256 + tx;
        int c = q >> 2, o = q & 3;                // chunk = (dim c, tokens 16o..16o+15)
        uint4 pk;
        pk.x = pk4_fp8(tile[o*16+ 0][c], tile[o*16+ 1][c], tile[o*16+ 2][c], tile[o*16+ 3][c]);
        pk.y = pk4_fp8(tile[o*16+ 4][c], tile[o*16+ 5][c], tile[o*16+ 6][c], tile[o*16+ 7][c]);
        pk.z = pk4_fp8(tile[o*16+ 8][c], tile[o*16+ 9][c], tile[o*16+10][c], tile[o*16+11][c]);
        pk.w = pk4_fp8(tile[o*16+12][c], tile[o*16+13][c], tile[o*16+14][c], tile[o*16+15][c]);
        // r-bit-3 half-swap: bakes the missing swizzle bit into the data so the
        // consumer's bank index depends on all 4 low row bits.
        uint4 outv = ((c >> 3) & 1) ? make_uint4(pk.z, pk.w, pk.x, pk.y) : pk;
        *(uint4*)(panel + c * 64 + o * 16) = outv;
    }
}

// ---------------------------------------------------------------- pass 3: pairwise raw Gram via MX-fp8 MFMA (32x32x64)
// Counted-vmcnt deep pipeline (T3+T4 port): pipeline unit = ONE 64-token
// panel-pair (A_s 8KB + B_s 8KB). 4-slot LDS ring (64 KB -> 2 blocks/CU,
// 4 waves/SIMD), prefetch depth 3, uniform s_waitcnt vmcnt(4) (never 0 in the
// loop), ONE barrier per panel-step. 8 waves in 2x4 grid; per wave 64x32 out =
// 2 x mfma_scale_f32_32x32x64_f8f6f4 per panel (K=64 = exactly one panel).
// Wraparound STAGE((s+3)&63) keeps the loop uniform; restaged panels land in
// slots whose readers already drained (race-checked via the end-of-iter
// lgkmcnt(0)+barrier).
__device__ __forceinline__ void gload16(const void* gsrc, void* ldst) {
    __builtin_amdgcn_global_load_lds(
        (const __attribute__((address_space(1))) unsigned int*)gsrc,
        (__attribute__((address_space(3))) unsigned int*)ldst,
        16, 0, 0);
}

// Register-resident gather: 4x ds_read_b64 -> v8i via constant-index inserts.
__device__ __forceinline__ v8i gather_frag(const unsigned char* rp,
                                           int o0, int o1, int o2, int o3) {
    v2i x0 = *(const v2i*)(rp + o0);
    v2i x1 = *(const v2i*)(rp + o1);
    v2i x2 = *(const v2i*)(rp + o2);
    v2i x3 = *(const v2i*)(rp + o3);
    v8i r;
    r[0] = x0[0]; r[1] = x0[1];
    r[2] = x1[0]; r[3] = x1[1];
    r[4] = x2[0]; r[5] = x2[1];
    r[6] = x3[0]; r[7] = x3[1];
    return r;
}

__global__ __launch_bounds__(512, 2)
void gram_kernel(const unsigned char* __restrict__ Xt, float* __restrict__ pairP) {
    const int kc = blockIdx.x;                    // K-chunk 0..3
    const int p  = blockIdx.y;                    // pair 0..119
    int i = 0, rem = p;
    while (rem >= NH - 1 - i) { rem -= NH - 1 - i; ++i; }
    const int j = i + 1 + rem;

    // 4-slot ring: slot = [A 8KB | B 8KB] = 16 KB; 64 KB total
    __shared__ alignas(16) unsigned char lds[4 * 2 * PANEL_BYTES];

    const int tx = threadIdx.x;
    const int w  = tx >> 6, l = tx & 63;
    const int wm = w >> 2, wn = w & 3;            // 2x4 wave grid; wave out 64x32
    const int l31 = l & 31, half = l >> 5;

    // Staging source swizzle (16B chunk level): cc = cl ^ ((r>>1)&3).
    // 512 threads cover one full 8 KB panel per gload16 issue.
    unsigned int goff;
    {
        int r0 = tx >> 2, cl0 = tx & 3;
        goff = (unsigned int)(r0 * 64 + (cl0 ^ ((r0 >> 1) & 3)) * 16);
    }
    const int lo = w * 1024;                      // wave-uniform LDS base
    const char* Abase = (const char*)Xt + ((size_t)i * NKT + (size_t)kc * KT_PER_CHUNK) * PANEL_BYTES;
    const char* Bbase = (const char*)Xt + ((size_t)j * NKT + (size_t)kc * KT_PER_CHUNK) * PANEL_BYTES;

    // stage one panel-pair (16 KB): 2 gload16 per thread
    auto STAGE = [&](int s, int slot) {
        const char* pa = Abase + (size_t)s * PANEL_BYTES;
        const char* pb = Bbase + (size_t)s * PANEL_BYTES;
        char* base = (char*)lds + slot * (2 * PANEL_BYTES);
        gload16(pa + goff, base + lo);
        gload16(pb + goff, base + PANEL_BYTES + lo);
    };

    f32x16 acc0, acc1;
    #pragma unroll
    for (int e = 0; e < 16; ++e) { acc0[e] = 0.f; acc1[e] = 0.f; }

    // Row-dependent unit swizzle (r == l31 mod 32 within a fragment; r-bit3 == l31-bit3)
    const int usw = (l31 & 6) | ((l31 >> 3) & 1);
    const int puo0 = (((half * 4) + 0) ^ usw) * 8;  // lane's 4 k-units (k = half*32..+31)
    const int puo1 = (((half * 4) + 1) ^ usw) * 8;
    const int puo2 = (((half * 4) + 2) ^ usw) * 8;
    const int puo3 = (((half * 4) + 3) ^ usw) * 8;
    const int offA0 = (wm * 64 +  0 + l31) * 64;            // mi=0 row-tile
    const int offA1 = (wm * 64 + 32 + l31) * 64;            // mi=1 row-tile
    const int offB  = PANEL_BYTES + (wn * 32 + l31) * 64;   // col-tile

    // ---- prologue: stage panels 0,1,2 into slots 0,1,2 (6 loads/thread in flight)
    STAGE(0, 0); STAGE(1, 1); STAGE(2, 2);
    asm volatile("s_waitcnt vmcnt(4)\n\ts_barrier" ::: "memory");   // slot0 ready

    for (int s = 0; s < SKT; ++s) {
        // issue prefetch (depth 3). Overwrites slot (s-1)&3 — its readers drained
        // at end of iter s-1 (lgkmcnt(0)+barrier).
        STAGE((s + 3) & (SKT - 1), (s + 3) & 3);

        const unsigned char* sb = lds + (s & 3) * (2 * PANEL_BYTES);
        __builtin_amdgcn_s_setprio(1);
        v8i a0 = gather_frag(sb + offA0, puo0, puo1, puo2, puo3);
        v8i a1 = gather_frag(sb + offA1, puo0, puo1, puo2, puo3);
        v8i b  = gather_frag(sb + offB,  puo0, puo1, puo2, puo3);
        acc0 = __builtin_amdgcn_mfma_scale_f32_32x32x64_f8f6f4(
            a0, b, acc0, 0, 0, 0, 0x7F7F7F7F, 0, 0x7F7F7F7F);
        acc1 = __builtin_amdgcn_mfma_scale_f32_32x32x64_f8f6f4(
            a1, b, acc1, 0, 0, 0, 0x7F7F7F7F, 0, 0x7F7F7F7F);
        __builtin_amdgcn_s_setprio(0);

        // counted wait: 6 loads in flight (s+1,s+2,s+3); wait oldest 2 -> slot for
        // s+1 is ready. Never vmcnt(0) in the loop. lgkm(0): our reads retired.
        asm volatile("s_waitcnt vmcnt(4) lgkmcnt(0)\n\ts_barrier" ::: "memory");
    }
    asm volatile("s_waitcnt vmcnt(0)" ::: "memory");  // drain wraparound stages

    // Epilogue: plain stores into this kc's slab. 32x32 C/D layout:
    // col = l31, row_local = (e&3) + 8*(e>>2) + 4*half  (shape-determined).
    float* pc = pairP + ((size_t)kc * NPAIRS + (size_t)p) * (DH * DH);
    #pragma unroll
    for (int e = 0; e < 16; ++e) {
        int rl = (e & 3) + 8 * (e >> 2) + 4 * half;
        int row = wm * 64 + rl;
        int col = wn * 32 + l31;
        pc[row * DH + col]        = acc0[e];
        pc[(row + 32) * DH + col] = acc1[e];
    }
}

// ---------------------------------------------------------------- pass 4: per-pair loss + final accumulate
// Sums the kc-slabs (float4-vectorized), normalizes, reduces.
__global__ void pair_reduce_kernel(const float* __restrict__ pairP, const float* __restrict__ G,
                                   const float* __restrict__ sum, const float* __restrict__ sumsq,
                                   float* __restrict__ out) {
    int p = blockIdx.x;
    int i = 0, rem = p;
    while (rem >= NH - 1 - i) { rem -= NH - 1 - i; ++i; }
    int j = i + 1 + rem;
    __shared__ float smui[DH], smuj[DH], sri[DH], srj[DH];
    {
        int t = threadIdx.x;
        int head = (t < DH) ? i : j;
        int d = t & (DH - 1);
        int c = head * DH + d;
        float m = sum[c] * (1.f / (float)N_TOK);
        float var = (sumsq[c] - (float)N_TOK * m * m) * (1.f / (float)(N_TOK - 1));
        var = fmaxf(var, 0.f);
        float r = 1.f / (sqrtf(var) + 1e-8f);
        if (t < DH) { smui[d] = m; sri[d] = r; }
        else        { smuj[d] = m; srj[d] = r; }
    }
    __syncthreads();
    const float invN = 1.f / (float)N_TOK;
    const size_t SLAB = (size_t)NPAIRS * DH * DH;     // floats per kc slab
    const float* base = pairP + (size_t)p * (DH * DH);
    float s = 0.f;
    for (int q = threadIdx.x; q < (DH * DH) / 4; q += 256) {
        float4 v = ((const float4*)base)[q];
        #pragma unroll
        for (int kc = 1; kc < KCHUNKS; ++kc) {
            float4 t = ((const float4*)(base + kc * SLAB))[q];
            v.x += t.x; v.y += t.y; v.z += t.z; v.w += t.w;
        }
        int d = q >> 5;                // 32 float4 per 128-col row
        int e0 = (q & 31) * 4;
        float md = smui[d], rd = sri[d];
        float cn, df;
        cn = (v.x * invN - md * smuj[e0 + 0]) * rd * srj[e0 + 0];
        df = cn - ((d == e0 + 0) ? 1.f : 0.f); s += df * df;
        cn = (v.y * invN - md * smuj[e0 + 1]) * rd * srj[e0 + 1];
        df = cn - ((d == e0 + 1) ? 1.f : 0.f); s += df * df;
        cn = (v.z * invN - md * smuj[e0 + 2]) * rd * srj[e0 + 2];
        df = cn - ((d == e0 + 2) ? 1.f : 0.f); s += df * df;
        cn = (v.w * invN - md * smuj[e0 + 3]) * rd * srj[e0 + 3];
        df = cn - ((d == e0 + 3) ? 1.f : 0.f); s += df * df;
    }
    for (int o = 32; o; o >>= 1) s += __shfl_down(s, o);
    __shared__ float red[4];
    if ((threadIdx.x & 63) == 0) red[threadIdx.x >> 6] = s;
    __syncthreads();
    if (threadIdx.x == 0) {
        float t = red[0] + red[1] + red[2] + red[3];
        float x = -15.99f * (G[i * NH + j] - 0.0f);
        float sp = (x > 20.f) ? x : log1pf(expf(x));
        float wgt = 0.929f + (1.f - 0.929f) * sp;
        atomicAdd(out, wgt * t * (1.f / (float)NPAIRS));
    }
}

// ---------------------------------------------------------------- launcher
extern "C" void kernel_launch(void* const* d_in, const int* in_sizes, int n_in,
                              void* d_out, int out_size, void* d_ws, size_t ws_size,
                              hipStream_t stream) {
    const float* X = (const float*)d_in[0];
    const float* G = (const float*)d_in[1];
    float* out = (float*)d_out;
    char* ws = (char*)d_ws;

    float*         sum   = (float*)(ws + SUM_OFF);
    float*         sumsq = (float*)(ws + SUMSQ_OFF);
    float*         pairP = (float*)(ws + PC_OFF);
    unsigned char* Xt    = (unsigned char*)(ws + XT_OFF);

    hipMemsetAsync(ws + SUM_OFF, 0, 16384, stream);                     // sum+sumsq
    hipMemsetAsync(d_out, 0, 4, stream);

    stats_transpose_kernel<<<dim3(16, 256), 256, 0, stream>>>(X, sum, sumsq, Xt);
    gram_kernel<<<dim3(KCHUNKS, NPAIRS), 512, 0, stream>>>(Xt, pairP);
    pair_reduce_kernel<<<NPAIRS, 256, 0, stream>>>(pairP, G, sum, sumsq, out);
}